// Round 5
// baseline (215.163 us; speedup 1.0000x reference)
//
#include <hip/hip_runtime.h>
#include <hip/hip_bf16.h>

// Gram-trick pipeline (B=8, C=512, T=4096, SCALE=512):
//   sx[b,c]   = sum_t x[b,c,t]           (fused into streaming convert)
//   G[b]      = x_b x_b^T                (bf16 MFMA, split-K=4 + reduce)   [symmetric]
//   middle    : tmp = Wqk_strip*G (NT via symmetry); scores = tmp*Wv^T + biases;
//               softmax_v + pb = p.bv;  M_strip = p*WvT      -- ONE kernel
//   out[b]    = M[b] x_b + pb            (NN: B=xh via subtiled LDS + ds_read_b64_tr_b16)

#define BB 8
#define CC 512
#define TT 4096

typedef __attribute__((ext_vector_type(8))) short bf16x8;
typedef __attribute__((ext_vector_type(4))) short bf16x4;
typedef __attribute__((ext_vector_type(4))) float f32x4;

__device__ __forceinline__ void gload_lds16(const void* g, void* l) {
  __builtin_amdgcn_global_load_lds((const __attribute__((address_space(1))) void*)g,
                                   (__attribute__((address_space(3))) void*)l,
                                   16, 0, 0);
}
__device__ __forceinline__ float bf2f(short u) {
  return __uint_as_float(((unsigned)(unsigned short)u) << 16);
}
__device__ __forceinline__ unsigned short f2bf(float f) {
  return __builtin_bit_cast(unsigned short, __float2bfloat16(f));
}

// ---- streaming convert x -> bf16 [c,t] + fused row-sum ---------------------
__global__ __launch_bounds__(256)
void convert_stream_kernel(const float* __restrict__ x, __hip_bfloat16* __restrict__ xh,
                           float* __restrict__ sx)
{
  const int gid = blockIdx.x * 256 + threadIdx.x;
#pragma unroll
  for (int it = 0; it < 4; it++) {
    const int chunk = it * 524288 + gid;          // 8-float chunk index
    const size_t base = (size_t)chunk * 8;
    const float4 a = *(const float4*)&x[base];
    const float4 c = *(const float4*)&x[base + 4];
    bf16x8 h;
    h[0] = (short)f2bf(a.x); h[1] = (short)f2bf(a.y);
    h[2] = (short)f2bf(a.z); h[3] = (short)f2bf(a.w);
    h[4] = (short)f2bf(c.x); h[5] = (short)f2bf(c.y);
    h[6] = (short)f2bf(c.z); h[7] = (short)f2bf(c.w);
    *(bf16x8*)&xh[base] = h;
    float s = ((a.x + a.y) + (a.z + a.w)) + ((c.x + c.y) + (c.z + c.w));
#pragma unroll
    for (int off = 32; off; off >>= 1) s += __shfl_xor(s, off);
    if ((threadIdx.x & 63) == 0) atomicAdd(&sx[chunk >> 9], s);  // 512 chunks/row, wave-uniform row
  }
}

// ---- weights -> bf16 (+WvT) AND ta/tb dot products (grid 3072) -------------
__global__ __launch_bounds__(256)
void prep_w_kernel(const float* __restrict__ Wqk, const float* __restrict__ Wv,
                   const float* __restrict__ sx,
                   __hip_bfloat16* __restrict__ Wqkh, __hip_bfloat16* __restrict__ Wvh,
                   __hip_bfloat16* __restrict__ WvT,
                   float* __restrict__ ta, float* __restrict__ tb)
{
  const int blk = blockIdx.x;
  if (blk < 1024) {
    int i = blk * 256 + threadIdx.x;  // < 512*512
    Wqkh[i] = __float2bfloat16(Wqk[i]);
    float wv = Wv[i];
    Wvh[i] = __float2bfloat16(wv);
    WvT[(i & 511) * 512 + (i >> 9)] = __float2bfloat16(wv);
  } else {
    int wid = threadIdx.x >> 6, lane = threadIdx.x & 63;
    int gid = (blk - 1024) * 4 + wid;  // [0, 8192) = 2 * 8 * 512 jobs
    int which = gid >> 12;
    int rem = gid & 4095;
    int b = rem >> 9, j = rem & 511;
    const float* W = which ? Wv : Wqk;
    float s = 0.f;
#pragma unroll
    for (int i2 = 0; i2 < 8; i2++) {
      int c = lane + i2 * 64;
      s += W[j * 512 + c] * sx[b * 512 + c];
    }
#pragma unroll
    for (int off = 32; off; off >>= 1) s += __shfl_xor(s, off);
    if (lane == 0) (which ? tb : ta)[b * 512 + j] = s;
  }
}

// ---- NT GEMM template: C = A[M,K] B[N,K]^T, 2-phase pipelined dbuf ---------
template <int BM, int BN, int EPI>
__global__ __launch_bounds__(256)
void gemm_nt_kernel(const __hip_bfloat16* __restrict__ A, long strideA, int ldA,
                    const __hip_bfloat16* __restrict__ B, long strideB, int ldB,
                    void* __restrict__ C, long strideC, int ldC,
                    int Kslice, int nslices)
{
  constexpr int FM = BM / 32, FN = BN / 32;
  const int tid = threadIdx.x, lane = tid & 63, wid = tid >> 6;

  const int gx = gridDim.x, gy = gridDim.y;
  const int lin = blockIdx.x + gx * (blockIdx.y + gy * blockIdx.z);
  const int nwg = gx * gy * (int)gridDim.z;
  const int lin2 = (lin & 7) * (nwg >> 3) + (lin >> 3);
  const int tn = lin2 % gx;
  const int r1 = lin2 / gx;
  const int tm = r1 % gy;
  const int z  = r1 / gy;
  const int b  = z / nslices;
  const int ks = z - b * nslices;

  const __hip_bfloat16* Ab = A + (size_t)b * strideA + (size_t)(tm * BM) * ldA + (size_t)ks * Kslice;
  const __hip_bfloat16* Bb = B + (size_t)b * strideB + (size_t)(tn * BN) * ldB + (size_t)ks * Kslice;

  __shared__ __align__(16) __hip_bfloat16 sA[2][BM * 64];
  __shared__ __align__(16) __hip_bfloat16 sB[2][BN * 64];

  const int wr = wid >> 1, wc = wid & 1;

  f32x4 acc[FM][FN];
#pragma unroll
  for (int m = 0; m < FM; m++)
#pragma unroll
    for (int n = 0; n < FN; n++) acc[m][n] = (f32x4){0.f, 0.f, 0.f, 0.f};

  auto stage = [&](int buf, int k0) {
#pragma unroll
    for (int i = 0; i < BM / 32; i++) {
      int e = tid * 8 + i * 2048;
      int row = e >> 6, colg = (e & 63) ^ ((row & 7) << 3);
      gload_lds16(Ab + (size_t)row * ldA + k0 + colg, &sA[buf][wid * 512 + i * 2048]);
    }
#pragma unroll
    for (int i = 0; i < BN / 32; i++) {
      int e = tid * 8 + i * 2048;
      int row = e >> 6, colg = (e & 63) ^ ((row & 7) << 3);
      gload_lds16(Bb + (size_t)row * ldB + k0 + colg, &sB[buf][wid * 512 + i * 2048]);
    }
  };

  stage(0, 0);
  __syncthreads();
  const int nsteps = Kslice >> 6;
  for (int s = 0; s < nsteps; s++) {
    if (s + 1 < nsteps) stage((s + 1) & 1, (s + 1) << 6);
    const __hip_bfloat16* cA = sA[s & 1];
    const __hip_bfloat16* cB = sB[s & 1];
#pragma unroll
    for (int ks2 = 0; ks2 < 2; ks2++) {
      bf16x8 af[FM], bfv[FN];
      const int kb = ks2 * 32 + (lane >> 4) * 8;
#pragma unroll
      for (int m = 0; m < FM; m++) {
        int row = wr * (BM / 2) + m * 16 + (lane & 15);
        af[m] = *(const bf16x8*)&cA[row * 64 + (kb ^ ((row & 7) << 3))];
      }
#pragma unroll
      for (int n = 0; n < FN; n++) {
        int row = wc * (BN / 2) + n * 16 + (lane & 15);
        bfv[n] = *(const bf16x8*)&cB[row * 64 + (kb ^ ((row & 7) << 3))];
      }
#pragma unroll
      for (int m = 0; m < FM; m++)
#pragma unroll
        for (int n = 0; n < FN; n++)
          acc[m][n] = __builtin_amdgcn_mfma_f32_16x16x32_bf16(af[m], bfv[n], acc[m][n], 0, 0, 0);
    }
    __syncthreads();
  }

  // epilogue (EPI==0: bf16 store). C/D: col = lane&15, row = (lane>>4)*4 + reg
  const int rb = tm * BM + wr * (BM / 2) + ((lane >> 4) << 2);
  const int cb = tn * BN + wc * (BN / 2) + (lane & 15);
  __hip_bfloat16* Cb = (__hip_bfloat16*)C + (size_t)z * strideC;
#pragma unroll
  for (int m = 0; m < FM; m++)
#pragma unroll
    for (int n = 0; n < FN; n++)
#pragma unroll
      for (int r = 0; r < 4; r++) {
        int row = rb + m * 16 + r, col = cb + n * 16;
        Cb[(size_t)row * ldC + col] = __float2bfloat16(acc[m][n][r]);
      }
}

// ---- reduce split-K bf16 partials -> bf16 G --------------------------------
__global__ __launch_bounds__(256)
void reduce_g_kernel(const short* __restrict__ Gpart, short* __restrict__ Gb)
{
  const int idx = (blockIdx.x * 256 + threadIdx.x) * 8;  // < BB*262144
  const int b = idx >> 18, i = idx & 262143;
  const short* base = Gpart + ((size_t)(b * 4) << 18) + i;
  float s[8];
#pragma unroll
  for (int q = 0; q < 8; q++) s[q] = 0.f;
#pragma unroll
  for (int ks = 0; ks < 4; ks++) {
    bf16x8 v = *(const bf16x8*)(base + ((size_t)ks << 18));
#pragma unroll
    for (int q = 0; q < 8; q++) s[q] += bf2f(v[q]);
  }
  bf16x8 o;
#pragma unroll
  for (int q = 0; q < 8; q++) o[q] = (short)f2bf(s[q]);
  *(bf16x8*)(Gb + ((size_t)b << 18) + i) = o;
}

// ---- middle: scores-chain fused. One block = 32 k-rows x 512, batch b ------
// stage1: tmp = Wqk_strip * G   (NT valid: G symmetric)
// stage2: scores = tmp * Wv^T + bqk*tb^T + ta*bv^T + T*bqk*bv^T, /512
// softmax over v (in-register, cross-wave via LDS) -> p (bf16, LDS), pb
// stage3: M_strip = p * WvT^T  (= p * Wv)
__global__ __launch_bounds__(256)
void middle_kernel(const __hip_bfloat16* __restrict__ Gh,
                   const __hip_bfloat16* __restrict__ Wqkh,
                   const __hip_bfloat16* __restrict__ Wvh,
                   const __hip_bfloat16* __restrict__ WvT,
                   const float* __restrict__ bqk, const float* __restrict__ bv,
                   const float* __restrict__ ta, const float* __restrict__ tb,
                   __hip_bfloat16* __restrict__ Mm, float* __restrict__ pb)
{
  __shared__ __align__(16) __hip_bfloat16 sW[32 * 512];   // Wqk strip (swizzled)
  __shared__ __align__(16) __hip_bfloat16 sT[32 * 512];   // tmp, then p (swizzled)
  __shared__ __align__(16) __hip_bfloat16 sB[512 * 64];   // B panel (swizzled)
  __shared__ float red1[4][32], red2[4][32], red3[4][32];

  const int tid = threadIdx.x, lane = tid & 63, wid = tid >> 6;
  const int strip = blockIdx.x, b = blockIdx.y;
  const __hip_bfloat16* Ghb = Gh + (size_t)b * 262144;

  // stage Wqk strip [32][512]: wave-linear dest, inverse-swizzled source
  {
    const __hip_bfloat16* As = Wqkh + (size_t)(strip * 32) * 512;
#pragma unroll
    for (int i = 0; i < 8; i++) {
      int row = i * 4 + wid;
      int scol = (lane * 8) ^ ((row & 7) << 3);
      gload_lds16(As + row * 512 + scol, &sW[i * 2048 + wid * 512]);
    }
  }

  // stage full B panel [512 rows][64 k] swizzled; rows are the NT "N" dim
  auto stageB = [&](const __hip_bfloat16* Bsrc, int k0) {
    const int r0 = wid * 8 + (lane >> 3);
    const int sc = k0 + 8 * ((lane & 7) ^ (lane >> 3));
#pragma unroll
    for (int i = 0; i < 16; i++)
      gload_lds16(Bsrc + (size_t)(i * 32 + r0) * 512 + sc, &sB[i * 2048 + wid * 512]);
  };

  f32x4 acc[2][8];

#define RUN_STAGE(BSRC, SX)                                                     \
  {                                                                             \
    _Pragma("unroll") for (int m = 0; m < 2; m++)                               \
      _Pragma("unroll") for (int n = 0; n < 8; n++)                             \
        acc[m][n] = (f32x4){0.f, 0.f, 0.f, 0.f};                                \
    for (int t = 0; t < 8; t++) {                                               \
      stageB(BSRC, t * 64);                                                     \
      __syncthreads();                                                          \
      _Pragma("unroll") for (int ks2 = 0; ks2 < 2; ks2++) {                     \
        const int kb = ks2 * 32 + (lane >> 4) * 8;                              \
        const int kq = t * 64 + kb;                                             \
        bf16x8 af[2], bfr[8];                                                   \
        _Pragma("unroll") for (int m = 0; m < 2; m++) {                         \
          int row = m * 16 + (lane & 15);                                       \
          af[m] = *(const bf16x8*)&SX[row * 512 + (kq ^ ((row & 7) << 3))];     \
        }                                                                       \
        _Pragma("unroll") for (int n = 0; n < 8; n++) {                         \
          int row = wid * 128 + n * 16 + (lane & 15);                           \
          bfr[n] = *(const bf16x8*)&sB[row * 64 + (kb ^ ((row & 7) << 3))];     \
        }                                                                       \
        _Pragma("unroll") for (int m = 0; m < 2; m++)                           \
          _Pragma("unroll") for (int n = 0; n < 8; n++)                         \
            acc[m][n] = __builtin_amdgcn_mfma_f32_16x16x32_bf16(af[m], bfr[n], acc[m][n], 0, 0, 0); \
      }                                                                         \
      __syncthreads();                                                          \
    }                                                                           \
  }

  // ---- stage 1: tmp = Wqk_strip * G
  RUN_STAGE(Ghb, sW);
  // write tmp -> sT (bf16, swizzled)
#pragma unroll
  for (int m = 0; m < 2; m++)
#pragma unroll
    for (int n = 0; n < 8; n++)
#pragma unroll
      for (int r = 0; r < 4; r++) {
        int rowl = m * 16 + ((lane >> 4) << 2) + r;
        int col = wid * 128 + n * 16 + (lane & 15);
        sT[rowl * 512 + (col ^ ((rowl & 7) << 3))] = __float2bfloat16(acc[m][n][r]);
      }
  __syncthreads();

  // ---- stage 2: scores = tmp * Wv^T
  RUN_STAGE(Wvh, sT);

  // biases + scale
  const float* tab = ta + b * 512;
  const float* tbb = tb + b * 512;
  float bq[2][4], tar[2][4], bvc[8], tbc[8];
#pragma unroll
  for (int m = 0; m < 2; m++)
#pragma unroll
    for (int r = 0; r < 4; r++) {
      int row = strip * 32 + m * 16 + ((lane >> 4) << 2) + r;
      bq[m][r] = bqk[row]; tar[m][r] = tab[row];
    }
#pragma unroll
  for (int n = 0; n < 8; n++) {
    int col = wid * 128 + n * 16 + (lane & 15);
    bvc[n] = bv[col]; tbc[n] = tbb[col];
  }
#pragma unroll
  for (int m = 0; m < 2; m++)
#pragma unroll
    for (int n = 0; n < 8; n++)
#pragma unroll
      for (int r = 0; r < 4; r++)
        acc[m][n][r] = (acc[m][n][r] + bq[m][r] * tbc[n] + tar[m][r] * bvc[n]
                        + 4096.0f * bq[m][r] * bvc[n]) * (1.0f / 512.0f);

  // row-max over this wave's 128 cols, then cross-wave
#pragma unroll
  for (int m = 0; m < 2; m++)
#pragma unroll
    for (int r = 0; r < 4; r++) {
      float v = acc[m][0][r];
#pragma unroll
      for (int n = 1; n < 8; n++) v = fmaxf(v, acc[m][n][r]);
#pragma unroll
      for (int off = 1; off < 16; off <<= 1) v = fmaxf(v, __shfl_xor(v, off));
      if ((lane & 15) == 0) red1[wid][m * 16 + ((lane >> 4) << 2) + r] = v;
    }
  __syncthreads();

  // exp + row-sum + pb partial
#pragma unroll
  for (int m = 0; m < 2; m++)
#pragma unroll
    for (int r = 0; r < 4; r++) {
      int lr = m * 16 + ((lane >> 4) << 2) + r;
      float mx = fmaxf(fmaxf(red1[0][lr], red1[1][lr]), fmaxf(red1[2][lr], red1[3][lr]));
      float s = 0.f, pbp = 0.f;
#pragma unroll
      for (int n = 0; n < 8; n++) {
        float e = __expf(acc[m][n][r] - mx);
        acc[m][n][r] = e;
        s += e;
        pbp += e * bvc[n];
      }
#pragma unroll
      for (int off = 1; off < 16; off <<= 1) {
        s += __shfl_xor(s, off);
        pbp += __shfl_xor(pbp, off);
      }
      if ((lane & 15) == 0) { red2[wid][lr] = s; red3[wid][lr] = pbp; }
    }
  __syncthreads();

  // p -> sT, pb -> global
#pragma unroll
  for (int m = 0; m < 2; m++)
#pragma unroll
    for (int r = 0; r < 4; r++) {
      int lr = m * 16 + ((lane >> 4) << 2) + r;
      float inv = 1.0f / (red2[0][lr] + red2[1][lr] + red2[2][lr] + red2[3][lr]);
      if (wid == 0 && (lane & 15) == 0)
        pb[b * 512 + strip * 32 + lr] =
            (red3[0][lr] + red3[1][lr] + red3[2][lr] + red3[3][lr]) * inv;
#pragma unroll
      for (int n = 0; n < 8; n++) {
        int col = wid * 128 + n * 16 + (lane & 15);
        sT[lr * 512 + (col ^ ((lr & 7) << 3))] = __float2bfloat16(acc[m][n][r] * inv);
      }
    }
  __syncthreads();

  // ---- stage 3: M = p * Wv   (NT with WvT)
  RUN_STAGE(WvT, sT);
#undef RUN_STAGE

  __hip_bfloat16* Mb = Mm + (size_t)b * 262144 + (size_t)(strip * 32) * 512;
#pragma unroll
  for (int m = 0; m < 2; m++)
#pragma unroll
    for (int n = 0; n < 8; n++)
#pragma unroll
      for (int r = 0; r < 4; r++) {
        int rowl = m * 16 + ((lane >> 4) << 2) + r;
        int col = wid * 128 + n * 16 + (lane & 15);
        Mb[rowl * 512 + col] = __float2bfloat16(acc[m][n][r]);
      }
}

// ---- out = M x + pb : NN GEMM, B=xh[v,t] via subtiled LDS + ds_read_b64_tr_b16
__global__ __launch_bounds__(256)
void gemm_out_kernel(const __hip_bfloat16* __restrict__ Mall,
                     const __hip_bfloat16* __restrict__ xh,
                     const float* __restrict__ pball,
                     float* __restrict__ out)
{
  __shared__ __align__(16) __hip_bfloat16 sA[2][128 * 64];
  __shared__ __align__(16) __hip_bfloat16 sB[2][64 * 128];

  const int tid = threadIdx.x, lane = tid & 63, wid = tid >> 6;
  const int wr = wid >> 1, wc = wid & 1;

  const int lin = blockIdx.x + 32 * (blockIdx.y + 4 * blockIdx.z);
  const int lin2 = (lin & 7) * 128 + (lin >> 3);
  const int tn = lin2 & 31;
  const int tm = (lin2 >> 5) & 3;
  const int b  = lin2 >> 7;

  const __hip_bfloat16* Ab = Mall + (size_t)b * 262144 + (size_t)(tm * 128) * 512;
  const __hip_bfloat16* Bb = xh + (size_t)b * ((size_t)CC * TT) + tn * 128;

  f32x4 acc[4][4];
#pragma unroll
  for (int m = 0; m < 4; m++)
#pragma unroll
    for (int n = 0; n < 4; n++) acc[m][n] = (f32x4){0.f, 0.f, 0.f, 0.f};

  auto stage = [&](int buf, int k0) {
#pragma unroll
    for (int i = 0; i < 4; i++) {   // A: [128 k][64 v] swizzled
      int e = tid * 8 + i * 2048;
      int row = e >> 6, colg = (e & 63) ^ ((row & 7) << 3);
      gload_lds16(Ab + (size_t)row * 512 + k0 + colg, &sA[buf][wid * 512 + i * 2048]);
    }
#pragma unroll
    for (int q = 0; q < 4; q++) {   // B: [64 v][128 t] in subtiled layout
      int E = q * 2048 + tid * 8;
      int v = ((E >> 9) << 2) | ((E >> 4) & 3);
      int t = (((E >> 6) & 7) << 4) | (E & 8);
      gload_lds16(Bb + (size_t)(k0 + v) * TT + t, &sB[buf][wid * 512 + q * 2048]);
    }
  };

  const unsigned sB32 =
      (unsigned)(size_t)(__attribute__((address_space(3))) __hip_bfloat16*)&sB[0][0];
  const unsigned btr_lo = sB32 + (lane >> 4) * 2048 + (lane & 15) * 8 + wc * 512;
  const unsigned btr_hi = btr_lo + 8192;

#define COMPUTE(BUF)                                                            \
  {                                                                             \
    _Pragma("unroll")                                                           \
    for (int ks2 = 0; ks2 < 2; ks2++) {                                         \
      bf16x8 af[4]; bf16x4 blo[4], bhi[4];                                      \
      const int kb = ks2 * 32 + (lane >> 4) * 8;                                \
      _Pragma("unroll")                                                         \
      for (int m = 0; m < 4; m++) {                                             \
        int row = wr * 64 + m * 16 + (lane & 15);                               \
        af[m] = *(const bf16x8*)&sA[BUF][row * 64 + (kb ^ ((row & 7) << 3))];   \
      }                                                                         \
      unsigned ab = ks2 ? btr_hi : btr_lo;                                      \
      _Pragma("unroll")                                                         \
      for (int n = 0; n < 4; n++) {                                             \
        asm volatile("ds_read_b64_tr_b16 %0, %1 offset:%2"                      \
                     : "=v"(blo[n]) : "v"(ab), "i"((BUF) * 16384 + n * 128));   \
        asm volatile("ds_read_b64_tr_b16 %0, %1 offset:%2"                      \
                     : "=v"(bhi[n]) : "v"(ab), "i"((BUF) * 16384 + n * 128 + 1024)); \
      }                                                                         \
      asm volatile("s_waitcnt lgkmcnt(0)" ::: "memory");                        \
      __builtin_amdgcn_sched_barrier(0);                                        \
      _Pragma("unroll")                                                         \
      for (int m = 0; m < 4; m++)                                               \
        _Pragma("unroll")                                                       \
        for (int n = 0; n < 4; n++) {                                           \
          bf16x8 b8 = __builtin_shufflevector(blo[n], bhi[n], 0, 1, 2, 3, 4, 5, 6, 7); \
          acc[m][n] = __builtin_amdgcn_mfma_f32_16x16x32_bf16(af[m], b8, acc[m][n], 0, 0, 0); \
        }                                                                       \
    }                                                                           \
  }

  stage(0, 0);
  __syncthreads();
#pragma unroll 1
  for (int s = 0; s < 8; s += 2) {
    if (s + 1 < 8) stage(1, (s + 1) * 64);
    COMPUTE(0);
    __syncthreads();
    if (s + 2 < 8) stage(0, (s + 2) * 64);
    COMPUTE(1);
    __syncthreads();
  }
#undef COMPUTE

  const int rb = tm * 128 + wr * 64 + ((lane >> 4) << 2);
  const int cb = tn * 128 + wc * 64 + (lane & 15);
  float* Cf = out + (size_t)b * ((size_t)CC * TT);
  const float* pbv = pball + b * 512;
#pragma unroll
  for (int m = 0; m < 4; m++)
#pragma unroll
    for (int n = 0; n < 4; n++)
#pragma unroll
      for (int r = 0; r < 4; r++) {
        int row = rb + m * 16 + r, col = cb + n * 16;
        Cf[(size_t)row * TT + col] = acc[m][n][r] + pbv[row];
      }
}

// ----------------------------------------------------------------------------
extern "C" void kernel_launch(void* const* d_in, const int* in_sizes, int n_in,
                              void* d_out, int out_size, void* d_ws, size_t ws_size,
                              hipStream_t stream)
{
  const float* x   = (const float*)d_in[0];
  const float* Wqk = (const float*)d_in[1];
  const float* bqk = (const float*)d_in[2];
  const float* Wv  = (const float*)d_in[3];
  const float* bv  = (const float*)d_in[4];
  float* out = (float*)d_out;

  char* w = (char*)d_ws;
  auto alloc = [&](size_t bytes) {
    void* pp = (void*)w;
    w += (bytes + 255) & ~(size_t)255;
    return pp;
  };
  __hip_bfloat16* xh     = (__hip_bfloat16*)alloc((size_t)BB * CC * TT * 2);
  short*          Gpart  = (short*)alloc((size_t)BB * 4 * CC * CC * 2);
  short*          Gb     = (short*)alloc((size_t)BB * CC * CC * 2);
  __hip_bfloat16* Mm     = (__hip_bfloat16*)alloc((size_t)BB * CC * CC * 2);
  __hip_bfloat16* Wqkh   = (__hip_bfloat16*)alloc((size_t)CC * CC * 2);
  __hip_bfloat16* Wvh    = (__hip_bfloat16*)alloc((size_t)CC * CC * 2);
  __hip_bfloat16* WvT    = (__hip_bfloat16*)alloc((size_t)CC * CC * 2);
  float* sx = (float*)alloc((size_t)BB * CC * 4);
  float* ta = (float*)alloc((size_t)BB * CC * 4);
  float* tb = (float*)alloc((size_t)BB * CC * 4);
  float* pb = (float*)alloc((size_t)BB * CC * 4);

  hipMemsetAsync(sx, 0, (size_t)BB * CC * 4, stream);

  convert_stream_kernel<<<2048, 256, 0, stream>>>(x, xh, sx);
  prep_w_kernel<<<3072, 256, 0, stream>>>(Wqk, Wv, sx, Wqkh, Wvh, WvT, ta, tb);

  const long sXH = (long)CC * TT;
  const long sSq = (long)CC * CC;

  // G = x x^T, split-K=4 (bf16 partials)
  gemm_nt_kernel<128, 128, 0><<<dim3(4, 4, BB * 4), 256, 0, stream>>>(
      xh, sXH, TT, xh, sXH, TT, Gpart, sSq, CC, 1024, 4);
  reduce_g_kernel<<<(BB * CC * CC) / (256 * 8), 256, 0, stream>>>(Gpart, Gb);

  // fused S2+scores+softmax+M
  middle_kernel<<<dim3(16, BB), 256, 0, stream>>>(
      (const __hip_bfloat16*)Gb, Wqkh, Wvh, WvT, bqk, bv, ta, tb, Mm, pb);

  // out = M x + pb (NN, tr_b16 staging of xh)
  gemm_out_kernel<<<dim3(32, 4, 8), 256, 0, stream>>>(Mm, xh, pb, out);
}